// Round 1
// baseline (386.992 us; speedup 1.0000x reference)
//
#include <hip/hip_runtime.h>

typedef unsigned short u16;
typedef unsigned int u32;
typedef __bf16 bf16x8 __attribute__((ext_vector_type(8)));
typedef float f32x4 __attribute__((ext_vector_type(4)));
typedef u16 u16x8 __attribute__((ext_vector_type(8)));
typedef u16 u16x4 __attribute__((ext_vector_type(4)));

#define LN_EPS 1e-5f
#define SIG_SCALE_F 0.35355339059327379f  /* 64^-0.25 */
#define ATTN_BIAS -3.0f

__device__ inline u16 f2bf(float f) {
    u32 u = __builtin_bit_cast(u32, f);
    u32 r = u + 0x7fffu + ((u >> 16) & 1u);
    return (u16)(r >> 16);
}

__device__ inline void store_c(float v, float* p) { *p = v; }
__device__ inline void store_c(float v, u16* p) { *p = f2bf(v); }

// ---------------------------------------------------------------------------
// C[M,N] = A[M,K] @ B[N,K]^T   (bf16 in, fp32 accumulate, OutT out)
// 128x128 tile, BK=32, 256 threads = 4 waves (2x2 of 64x64), 16 MFMA/wave/kstep
// ---------------------------------------------------------------------------
template <typename OutT>
__global__ __launch_bounds__(256) void gemm_bt(const u16* __restrict__ A,
                                               const u16* __restrict__ B,
                                               OutT* __restrict__ C,
                                               int M, int N, int K) {
    __shared__ u16 As[128 * 40];  // pad 32->40 shorts: 2-way banks only (free)
    __shared__ u16 Bs[128 * 40];
    const int tid  = threadIdx.x;
    const int lane = tid & 63;
    const int wave = tid >> 6;
    const int r15  = lane & 15;
    const int qd   = lane >> 4;
    const int wm   = (wave >> 1) * 64;
    const int wn   = (wave & 1) * 64;
    const long m0  = (long)blockIdx.x * 128;
    const long n0  = (long)blockIdx.y * 128;

    const int sr = tid >> 1;        // 0..127
    const int sc = (tid & 1) * 16;  // 0 or 16

    f32x4 acc[4][4];
#pragma unroll
    for (int i = 0; i < 4; i++)
#pragma unroll
        for (int j = 0; j < 4; j++) acc[i][j] = (f32x4){0.f, 0.f, 0.f, 0.f};

    for (int kt = 0; kt < K; kt += 32) {
        u16x8 a0 = *(const u16x8*)(A + (m0 + sr) * K + kt + sc);
        u16x8 a1 = *(const u16x8*)(A + (m0 + sr) * K + kt + sc + 8);
        u16x8 b0 = *(const u16x8*)(B + (n0 + sr) * K + kt + sc);
        u16x8 b1 = *(const u16x8*)(B + (n0 + sr) * K + kt + sc + 8);
        __syncthreads();  // previous iteration's LDS reads complete
        *(u16x8*)&As[sr * 40 + sc]     = a0;
        *(u16x8*)&As[sr * 40 + sc + 8] = a1;
        *(u16x8*)&Bs[sr * 40 + sc]     = b0;
        *(u16x8*)&Bs[sr * 40 + sc + 8] = b1;
        __syncthreads();
        bf16x8 af[4], bfr[4];
#pragma unroll
        for (int i = 0; i < 4; i++)
            af[i] = *(const bf16x8*)&As[(wm + i * 16 + r15) * 40 + qd * 8];
#pragma unroll
        for (int j = 0; j < 4; j++)
            bfr[j] = *(const bf16x8*)&Bs[(wn + j * 16 + r15) * 40 + qd * 8];
#pragma unroll
        for (int i = 0; i < 4; i++)
#pragma unroll
            for (int j = 0; j < 4; j++)
                acc[i][j] = __builtin_amdgcn_mfma_f32_16x16x32_bf16(af[i], bfr[j], acc[i][j], 0, 0, 0);
    }

#pragma unroll
    for (int i = 0; i < 4; i++) {
#pragma unroll
        for (int rr = 0; rr < 4; rr++) {
            long row = m0 + wm + i * 16 + qd * 4 + rr;
#pragma unroll
            for (int j = 0; j < 4; j++) {
                long col = n0 + wn + j * 16 + r15;
                store_c(acc[i][j][rr], &C[row * N + col]);
            }
        }
    }
}

// ---------------------------------------------------------------------------
// Fused sigmoid cross-attention per (b, h, 64-row q tile).
// ctx[bq, h*64+d] = sum_k sigmoid(q.k - 3) * v[k,d]
// q,k,v: [4096, 1024] bf16 (head h occupies cols h*64..h*64+63)
// ---------------------------------------------------------------------------
__global__ __launch_bounds__(256) void attn_sigmoid(const u16* __restrict__ q,
                                                    const u16* __restrict__ k,
                                                    const u16* __restrict__ v,
                                                    u16* __restrict__ ctx) {
    __shared__ u16 Qs[64 * 72];
    __shared__ u16 Ks[64 * 72];
    __shared__ u16 Vt[64 * 72];      // V transposed: Vt[d][kk]
    __shared__ u16 Ps[4][16 * 72];   // per-wave P tile (C-layout -> A-layout)
    const int tid  = threadIdx.x;
    const int lane = tid & 63;
    const int wave = tid >> 6;
    const int r15  = lane & 15;
    const int qd   = lane >> 4;
    const int q0   = blockIdx.x * 64;
    const int h    = blockIdx.y;
    const int b    = blockIdx.z;
    const int NQ = 2048, NK = 2048, AD = 1024;
    const int colbase = h * 64;

    const int sr = tid >> 2;        // 0..63
    const int sc = (tid & 3) * 16;  // 0,16,32,48

    {   // stage Q tile (sync covered by first in-loop barrier)
        const u16* src = q + (size_t)(b * NQ + q0 + sr) * AD + colbase + sc;
        u16x8 v0 = *(const u16x8*)src;
        u16x8 v1 = *(const u16x8*)(src + 8);
        *(u16x8*)&Qs[sr * 72 + sc]     = v0;
        *(u16x8*)&Qs[sr * 72 + sc + 8] = v1;
    }

    f32x4 accO[4];
#pragma unroll
    for (int j = 0; j < 4; j++) accO[j] = (f32x4){0.f, 0.f, 0.f, 0.f};

    for (int kc = 0; kc < NK; kc += 64) {
        {   // stage K chunk + transposed V chunk
            const u16* ksrc = k + (size_t)(b * NK + kc + sr) * AD + colbase + sc;
            u16x8 k0 = *(const u16x8*)ksrc;
            u16x8 k1 = *(const u16x8*)(ksrc + 8);
            *(u16x8*)&Ks[sr * 72 + sc]     = k0;
            *(u16x8*)&Ks[sr * 72 + sc + 8] = k1;
            const u16* vsrc = v + (size_t)(b * NK + kc + sr) * AD + colbase + sc;
            u16x8 w0 = *(const u16x8*)vsrc;
            u16x8 w1 = *(const u16x8*)(vsrc + 8);
#pragma unroll
            for (int i = 0; i < 8; i++) Vt[(sc + i) * 72 + sr] = w0[i];
#pragma unroll
            for (int i = 0; i < 8; i++) Vt[(sc + 8 + i) * 72 + sr] = w1[i];
        }
        __syncthreads();

        // S = Q_w (16x64) @ K^T (64x64)
        f32x4 accS[4];
#pragma unroll
        for (int j = 0; j < 4; j++) accS[j] = (f32x4){0.f, 0.f, 0.f, 0.f};
#pragma unroll
        for (int ks = 0; ks < 64; ks += 32) {
            bf16x8 aq = *(const bf16x8*)&Qs[(wave * 16 + r15) * 72 + ks + qd * 8];
#pragma unroll
            for (int j = 0; j < 4; j++) {
                bf16x8 bk = *(const bf16x8*)&Ks[(j * 16 + r15) * 72 + ks + qd * 8];
                accS[j] = __builtin_amdgcn_mfma_f32_16x16x32_bf16(aq, bk, accS[j], 0, 0, 0);
            }
        }
        // sigmoid, write P to LDS in C-layout positions (wave-private)
#pragma unroll
        for (int j = 0; j < 4; j++)
#pragma unroll
            for (int rr = 0; rr < 4; rr++) {
                float s = accS[j][rr] + ATTN_BIAS;
                float p = 1.0f / (1.0f + __expf(-s));
                Ps[wave][(qd * 4 + rr) * 72 + j * 16 + r15] = f2bf(p);
            }
        asm volatile("s_waitcnt lgkmcnt(0)" ::: "memory");
        // O += P (16x64) @ V (64x64)
#pragma unroll
        for (int ks = 0; ks < 64; ks += 32) {
            bf16x8 ap = *(const bf16x8*)&Ps[wave][r15 * 72 + ks + qd * 8];
#pragma unroll
            for (int j = 0; j < 4; j++) {
                bf16x8 bv = *(const bf16x8*)&Vt[(j * 16 + r15) * 72 + ks + qd * 8];
                accO[j] = __builtin_amdgcn_mfma_f32_16x16x32_bf16(ap, bv, accO[j], 0, 0, 0);
            }
        }
        __syncthreads();  // before K/V restage
    }

#pragma unroll
    for (int j = 0; j < 4; j++)
#pragma unroll
        for (int rr = 0; rr < 4; rr++) {
            int row = b * NQ + q0 + wave * 16 + qd * 4 + rr;
            ctx[(size_t)row * AD + colbase + j * 16 + r15] = f2bf(accO[j][rr]);
        }
}

// ---------------------------------------------------------------------------
// Row LayerNorm over D=1024 (fp32 in -> bf16 out), one block per row
// ---------------------------------------------------------------------------
__global__ __launch_bounds__(256) void ln_rows_bf16(const float* __restrict__ x,
                                                    const float* __restrict__ sc,
                                                    const float* __restrict__ bs,
                                                    u16* __restrict__ y) {
    __shared__ float s1buf[4], s2buf[4];
    const int row = blockIdx.x;
    const int tid = threadIdx.x;
    const size_t base = (size_t)row * 1024 + tid * 4;
    const float4 xv = *(const float4*)(x + base);
    float s1 = xv.x + xv.y + xv.z + xv.w;
    float s2 = xv.x * xv.x + xv.y * xv.y + xv.z * xv.z + xv.w * xv.w;
    int lane = tid & 63, wave = tid >> 6;
#pragma unroll
    for (int off = 32; off > 0; off >>= 1) {
        s1 += __shfl_down(s1, off, 64);
        s2 += __shfl_down(s2, off, 64);
    }
    if (lane == 0) { s1buf[wave] = s1; s2buf[wave] = s2; }
    __syncthreads();
    s1 = s1buf[0] + s1buf[1] + s1buf[2] + s1buf[3];
    s2 = s2buf[0] + s2buf[1] + s2buf[2] + s2buf[3];
    float mu = s1 * (1.0f / 1024.0f);
    float var = s2 * (1.0f / 1024.0f) - mu * mu;
    float rs = rsqrtf(var + LN_EPS);
    const float4 scv = *(const float4*)(sc + tid * 4);
    const float4 bsv = *(const float4*)(bs + tid * 4);
    u16x4 o;
    o[0] = f2bf((xv.x - mu) * rs * scv.x + bsv.x);
    o[1] = f2bf((xv.y - mu) * rs * scv.y + bsv.y);
    o[2] = f2bf((xv.z - mu) * rs * scv.z + bsv.z);
    o[3] = f2bf((xv.w - mu) * rs * scv.w + bsv.w);
    *(u16x4*)(y + base) = o;
}

// ---------------------------------------------------------------------------
// Per-head LayerNorm over 64 dims + SIG_SCALE, one wave per (row, head)
// ---------------------------------------------------------------------------
__global__ __launch_bounds__(256) void head_ln(const float* __restrict__ xp,
                                               const float* __restrict__ sc,
                                               const float* __restrict__ bs,
                                               u16* __restrict__ y) {
    const int tid = threadIdx.x;
    const int lane = tid & 63;
    const int gw = blockIdx.x * 4 + (tid >> 6);
    const int row = gw >> 4;
    const int h = gw & 15;
    const size_t idx = (size_t)row * 1024 + h * 64 + lane;
    float v = xp[idx];
    float s1 = v, s2 = v * v;
#pragma unroll
    for (int off = 32; off > 0; off >>= 1) {
        s1 += __shfl_xor(s1, off, 64);
        s2 += __shfl_xor(s2, off, 64);
    }
    float mu = s1 * (1.0f / 64.0f);
    float var = s2 * (1.0f / 64.0f) - mu * mu;
    float rs = rsqrtf(var + LN_EPS);
    float o = ((v - mu) * rs * sc[lane] + bs[lane]) * SIG_SCALE_F;
    y[idx] = f2bf(o);
}

// ---------------------------------------------------------------------------
// Final: out = LN(resid + gamma*op) with ln_out scale/bias (all fp32)
// ---------------------------------------------------------------------------
__global__ __launch_bounds__(256) void final_ln(const float* __restrict__ resid,
                                                const float* __restrict__ op,
                                                const float* __restrict__ gamma,
                                                const float* __restrict__ sc,
                                                const float* __restrict__ bs,
                                                float* __restrict__ out) {
    __shared__ float s1buf[4], s2buf[4];
    const int row = blockIdx.x;
    const int tid = threadIdx.x;
    const size_t base = (size_t)row * 1024 + tid * 4;
    float4 rv = *(const float4*)(resid + base);
    float4 ov = *(const float4*)(op + base);
    float4 gv = *(const float4*)(gamma + tid * 4);
    float4 xv;
    xv.x = rv.x + gv.x * ov.x;
    xv.y = rv.y + gv.y * ov.y;
    xv.z = rv.z + gv.z * ov.z;
    xv.w = rv.w + gv.w * ov.w;
    float s1 = xv.x + xv.y + xv.z + xv.w;
    float s2 = xv.x * xv.x + xv.y * xv.y + xv.z * xv.z + xv.w * xv.w;
    int lane = tid & 63, wave = tid >> 6;
#pragma unroll
    for (int off = 32; off > 0; off >>= 1) {
        s1 += __shfl_down(s1, off, 64);
        s2 += __shfl_down(s2, off, 64);
    }
    if (lane == 0) { s1buf[wave] = s1; s2buf[wave] = s2; }
    __syncthreads();
    s1 = s1buf[0] + s1buf[1] + s1buf[2] + s1buf[3];
    s2 = s2buf[0] + s2buf[1] + s2buf[2] + s2buf[3];
    float mu = s1 * (1.0f / 1024.0f);
    float var = s2 * (1.0f / 1024.0f) - mu * mu;
    float rs = rsqrtf(var + LN_EPS);
    const float4 scv = *(const float4*)(sc + tid * 4);
    const float4 bsv = *(const float4*)(bs + tid * 4);
    float4 o;
    o.x = (xv.x - mu) * rs * scv.x + bsv.x;
    o.y = (xv.y - mu) * rs * scv.y + bsv.y;
    o.z = (xv.z - mu) * rs * scv.z + bsv.z;
    o.w = (xv.w - mu) * rs * scv.w + bsv.w;
    *(float4*)(out + base) = o;
}

// ---------------------------------------------------------------------------
// fp32 -> bf16 convert (float4 granularity)
// ---------------------------------------------------------------------------
__global__ __launch_bounds__(256) void conv_bf16(const float* __restrict__ x,
                                                 u16* __restrict__ y, int n4) {
    int i = blockIdx.x * 256 + threadIdx.x;
    if (i < n4) {
        float4 xv = *(const float4*)(x + (size_t)i * 4);
        u16x4 o;
        o[0] = f2bf(xv.x);
        o[1] = f2bf(xv.y);
        o[2] = f2bf(xv.z);
        o[3] = f2bf(xv.w);
        *(u16x4*)(y + (size_t)i * 4) = o;
    }
}

extern "C" void kernel_launch(void* const* d_in, const int* in_sizes, int n_in,
                              void* d_out, int out_size, void* d_ws, size_t ws_size,
                              hipStream_t stream) {
    const float* qf    = (const float*)d_in[0];
    const float* kf    = (const float*)d_in[1];
    const float* Wq    = (const float*)d_in[2];
    const float* Wk    = (const float*)d_in[3];
    const float* Wv    = (const float*)d_in[4];
    const float* Wo    = (const float*)d_in[5];
    const float* qn_s  = (const float*)d_in[6];
    const float* qn_b  = (const float*)d_in[7];
    const float* kn_s  = (const float*)d_in[8];
    const float* kn_b  = (const float*)d_in[9];
    const float* lnq_s = (const float*)d_in[10];
    const float* lnq_b = (const float*)d_in[11];
    const float* lno_s = (const float*)d_in[12];
    const float* lno_b = (const float*)d_in[13];
    const float* gamma = (const float*)d_in[14];
    float* out = (float*)d_out;

    char* ws = (char*)d_ws;
    const size_t MB = 1024 * 1024;
    // layout with lifetime reuse (64 MiB total):
    u16* Wqb   = (u16*)(ws + 0 * MB);
    u16* Wkb   = (u16*)(ws + 2 * MB);
    u16* Wvb   = (u16*)(ws + 4 * MB);
    u16* Wob   = (u16*)(ws + 6 * MB);
    u16* xq    = (u16*)(ws + 8 * MB);    // dead after q-gemm
    u16* keyb  = (u16*)(ws + 16 * MB);   // dead after v-gemm
    float* qpre = (float*)(ws + 24 * MB); // dead after head_ln(q)
    float* kpre = (float*)(ws + 40 * MB); // dead after head_ln(k)
    u16* qln   = (u16*)(ws + 8 * MB);    // reuse xq slot
    u16* kln   = (u16*)(ws + 16 * MB);   // reuse keyb slot
    u16* vb    = (u16*)(ws + 56 * MB);
    u16* ctx   = (u16*)(ws + 24 * MB);   // reuse qpre slot
    float* opre = (float*)(ws + 40 * MB); // reuse kpre slot

    conv_bf16<<<dim3(4096), 256, 0, stream>>>(kf, keyb, 1048576);
    conv_bf16<<<dim3(1024), 256, 0, stream>>>(Wq, Wqb, 262144);
    conv_bf16<<<dim3(1024), 256, 0, stream>>>(Wk, Wkb, 262144);
    conv_bf16<<<dim3(1024), 256, 0, stream>>>(Wv, Wvb, 262144);
    conv_bf16<<<dim3(1024), 256, 0, stream>>>(Wo, Wob, 262144);
    ln_rows_bf16<<<dim3(4096), 256, 0, stream>>>(qf, lnq_s, lnq_b, xq);

    gemm_bt<float><<<dim3(32, 8), 256, 0, stream>>>(xq, Wqb, qpre, 4096, 1024, 1024);
    gemm_bt<float><<<dim3(32, 8), 256, 0, stream>>>(keyb, Wkb, kpre, 4096, 1024, 1024);
    gemm_bt<u16><<<dim3(32, 8), 256, 0, stream>>>(keyb, Wvb, vb, 4096, 1024, 1024);

    head_ln<<<dim3(16384), 256, 0, stream>>>(qpre, qn_s, qn_b, qln);
    head_ln<<<dim3(16384), 256, 0, stream>>>(kpre, kn_s, kn_b, kln);

    attn_sigmoid<<<dim3(32, 16, 2), 256, 0, stream>>>(qln, kln, vb, ctx);

    gemm_bt<float><<<dim3(32, 8), 256, 0, stream>>>(ctx, Wob, opre, 4096, 1024, 1024);
    final_ln<<<dim3(4096), 256, 0, stream>>>(qf, opre, gamma, lno_s, lno_b, out);
}

// Round 3
// 281.955 us; speedup vs baseline: 1.3725x; 1.3725x over previous
//
#include <hip/hip_runtime.h>

typedef unsigned short u16;
typedef unsigned int u32;
typedef __bf16 bf16x8 __attribute__((ext_vector_type(8)));
typedef float f32x4 __attribute__((ext_vector_type(4)));
typedef u16 u16x8 __attribute__((ext_vector_type(8)));
typedef u16 u16x4 __attribute__((ext_vector_type(4)));

#define LN_EPS 1e-5f
#define SIG_SCALE_F 0.35355339059327379f /* 64^-0.25 */
#define NLOG2E -1.4426950408889634f
#define BIAS_L2E 4.328085122666891f /* 3*log2(e); sigmoid(s-3)=rcp(1+2^(-s*log2e+3*log2e)) */

__device__ __forceinline__ u16 f2bf(float f) {
    u32 u = __builtin_bit_cast(u32, f);
    u32 r = u + 0x7fffu + ((u >> 16) & 1u);
    return (u16)(r >> 16);
}
__device__ __forceinline__ float bf2f(u16 v) {
    return __builtin_bit_cast(float, (u32)v << 16);
}
__device__ __forceinline__ u32 pkbf(float a, float b) {
    return (u32)f2bf(a) | ((u32)f2bf(b) << 16);
}
__device__ __forceinline__ void store_c(float v, float* p) { *p = v; }
__device__ __forceinline__ void store_c(float v, u16* p) { *p = f2bf(v); }

// async global->LDS, 16B per lane; lds must be wave-uniform base (HW adds lane*16)
__device__ __forceinline__ void gload16(const u16* g, u16* lds) {
    __builtin_amdgcn_global_load_lds(
        (const __attribute__((address_space(1))) u32*)g,
        (__attribute__((address_space(3))) u32*)lds, 16, 0, 0);
}

// ---------------------------------------------------------------------------
// m97-style GEMM body: C[M,N] = A[M,K] @ B[N,K]^T, 128x128 tile, BK=32,
// global_load_lds staging, XOR-swizzled LDS (rows of 64B, chunk c^=row&3).
// ---------------------------------------------------------------------------
template <typename OutT>
__device__ __forceinline__ void gemm_body(const u16* __restrict__ A, const u16* __restrict__ B,
                                          OutT* __restrict__ C, int K, int N,
                                          long m0, long n0, u16* As, u16* Bs) {
    const int tid = threadIdx.x;
    const int lane = tid & 63;
    const int wave = tid >> 6;
    const int r15 = lane & 15;
    const int qd = lane >> 4;
    const int wm = (wave >> 1) * 64;
    const int wn = (wave & 1) * 64;

    f32x4 acc[4][4];
#pragma unroll
    for (int i = 0; i < 4; i++)
#pragma unroll
        for (int j = 0; j < 4; j++) acc[i][j] = (f32x4){0.f, 0.f, 0.f, 0.f};

    // staging: segment s covers rows [s*16, s*16+16); wave w owns segs {w, w+4}
    const int srow = wave * 16 + (lane >> 2);
    const int c0 = (lane & 3) ^ (srow & 3);  // (srow+64)&3 == srow&3
    const u16* Ap0 = A + (m0 + srow) * K + c0 * 8;
    const u16* Ap1 = A + (m0 + srow + 64) * K + c0 * 8;
    const u16* Bp0 = B + (n0 + srow) * K + c0 * 8;
    const u16* Bp1 = B + (n0 + srow + 64) * K + c0 * 8;
    u16* As0 = As + wave * 512;
    u16* As1 = As + (wave + 4) * 512;
    u16* Bs0 = Bs + wave * 512;
    u16* Bs1 = Bs + (wave + 4) * 512;

    for (int kt = 0; kt < K; kt += 32) {
        __syncthreads();  // prior iteration's LDS reads done
        gload16(Ap0 + kt, As0);
        gload16(Ap1 + kt, As1);
        gload16(Bp0 + kt, Bs0);
        gload16(Bp1 + kt, Bs1);
        __syncthreads();  // drains vmcnt -> data resident
        bf16x8 af[4], bfr[4];
#pragma unroll
        for (int i = 0; i < 4; i++) {
            int row = wm + i * 16 + r15;
            af[i] = *(const bf16x8*)(As + row * 32 + ((qd ^ (row & 3)) * 8));
        }
#pragma unroll
        for (int j = 0; j < 4; j++) {
            int row = wn + j * 16 + r15;
            bfr[j] = *(const bf16x8*)(Bs + row * 32 + ((qd ^ (row & 3)) * 8));
        }
#pragma unroll
        for (int i = 0; i < 4; i++)
#pragma unroll
            for (int j = 0; j < 4; j++)
                acc[i][j] = __builtin_amdgcn_mfma_f32_16x16x32_bf16(af[i], bfr[j], acc[i][j], 0, 0, 0);
    }

#pragma unroll
    for (int i = 0; i < 4; i++) {
#pragma unroll
        for (int rr = 0; rr < 4; rr++) {
            long row = m0 + wm + i * 16 + qd * 4 + rr;
#pragma unroll
            for (int j = 0; j < 4; j++) {
                long col = n0 + wn + j * 16 + r15;
                store_c(acc[i][j][rr], &C[row * N + col]);
            }
        }
    }
}

// fused q/k/v projections: grid (32, 8, 3)
__global__ __launch_bounds__(256) void gemm_qkv(const u16* __restrict__ xq, const u16* __restrict__ keyb,
                                                const u16* __restrict__ Wqb, const u16* __restrict__ Wkb,
                                                const u16* __restrict__ Wvb,
                                                u16* __restrict__ qpre, u16* __restrict__ kpre,
                                                u16* __restrict__ vb) {
    __shared__ __attribute__((aligned(16))) u16 As[128 * 32];
    __shared__ __attribute__((aligned(16))) u16 Bs[128 * 32];
    const int z = blockIdx.z;
    const u16* A = (z == 0) ? xq : keyb;
    const u16* B = (z == 0) ? Wqb : ((z == 1) ? Wkb : Wvb);
    u16* C = (z == 0) ? qpre : ((z == 1) ? kpre : vb);
    gemm_body<u16>(A, B, C, 1024, 1024, (long)blockIdx.x * 128, (long)blockIdx.y * 128, As, Bs);
}

// output projection: grid (32, 8)
__global__ __launch_bounds__(256) void gemm_o(const u16* __restrict__ ctx, const u16* __restrict__ Wob,
                                              float* __restrict__ opre) {
    __shared__ __attribute__((aligned(16))) u16 As[128 * 32];
    __shared__ __attribute__((aligned(16))) u16 Bs[128 * 32];
    gemm_body<float>(ctx, Wob, opre, 1024, 1024, (long)blockIdx.x * 128, (long)blockIdx.y * 128, As, Bs);
}

// ---------------------------------------------------------------------------
// Fused sigmoid attention. Grid (Nq/128, H, B), 256 thr (4 waves x 32 q-rows).
// Computes S^T = K·Q^T per 64-k chunk so P lands with 4 consecutive k per lane
// (vectorized ds_write_b64 into A-operand layout), then O += P·V via
// pre-transposed V. K/V/Q staged with global_load_lds + XOR swizzle (rows of
// 128B, chunk c ^= row&7).
// ---------------------------------------------------------------------------
__device__ __forceinline__ bf16x8 frag64(const u16* base, int row, int kidx) {
    return *(const bf16x8*)(base + row * 64 + ((kidx ^ (row & 7)) * 8));
}

__global__ __launch_bounds__(256) void attn_sigmoid_v2(const u16* __restrict__ q,
                                                       const u16* __restrict__ k,
                                                       const u16* __restrict__ vt,
                                                       u16* __restrict__ ctx) {
    __shared__ __attribute__((aligned(16))) u16 Qs[128 * 64];
    __shared__ __attribute__((aligned(16))) u16 Ks[64 * 64];
    __shared__ __attribute__((aligned(16))) u16 Vs[64 * 64];
    __shared__ __attribute__((aligned(16))) u16 Ps[4][32 * 72];
    const int tid = threadIdx.x;
    const int lane = tid & 63;
    const int wave = tid >> 6;
    const int r15 = lane & 15;
    const int qd = lane >> 4;
    const int q0 = blockIdx.x * 128;
    const int h = blockIdx.y;
    const int b = blockIdx.z;
    const int bh = b * 16 + h;
    u16* Psw = &Ps[wave][0];

    // stage Q tile (128 rows x 64 cols), 16 segs, wave w owns segs 4w..4w+3
    {
        const int lr0 = lane >> 3;       // 0..7 rows within seg
        const int lc0 = lane & 7;        // chunk slot
#pragma unroll
        for (int i = 0; i < 4; i++) {
            int s = wave * 4 + i;
            int row = s * 8 + lr0;
            int c = lc0 ^ (row & 7);
            gload16(q + (size_t)(b * 2048 + q0 + row) * 1024 + h * 64 + c * 8, Qs + s * 512);
        }
    }

    f32x4 accO[2][4];
#pragma unroll
    for (int ms = 0; ms < 2; ms++)
#pragma unroll
        for (int jt = 0; jt < 4; jt++) accO[ms][jt] = (f32x4){0.f, 0.f, 0.f, 0.f};

    const int lr = lane >> 3;
    const int lc = lane & 7;

    for (int kc = 0; kc < 2048; kc += 64) {
        __syncthreads();  // prior chunk's LDS reads done
#pragma unroll
        for (int i = 0; i < 2; i++) {
            int s = wave * 2 + i;
            int row = s * 8 + lr;
            int c = lc ^ (row & 7);
            gload16(k + (size_t)(b * 2048 + kc + row) * 1024 + h * 64 + c * 8, Ks + s * 512);
            gload16(vt + (size_t)(bh * 64 + row) * 2048 + kc + c * 8, Vs + s * 512);
        }
        __syncthreads();  // vmcnt drain

        // S^T[k][q]: A = K frag (m=k), B = Q frag (n=q)
        f32x4 accS[4][2];
#pragma unroll
        for (int mt = 0; mt < 4; mt++)
#pragma unroll
            for (int s2 = 0; s2 < 2; s2++) accS[mt][s2] = (f32x4){0.f, 0.f, 0.f, 0.f};
#pragma unroll
        for (int ks = 0; ks < 64; ks += 32) {
            int kidx = (ks >> 3) + qd;
            bf16x8 bq0 = frag64(Qs, wave * 32 + r15, kidx);
            bf16x8 bq1 = frag64(Qs, wave * 32 + 16 + r15, kidx);
#pragma unroll
            for (int mt = 0; mt < 4; mt++) {
                bf16x8 ak = frag64(Ks, mt * 16 + r15, kidx);
                accS[mt][0] = __builtin_amdgcn_mfma_f32_16x16x32_bf16(ak, bq0, accS[mt][0], 0, 0, 0);
                accS[mt][1] = __builtin_amdgcn_mfma_f32_16x16x32_bf16(ak, bq1, accS[mt][1], 0, 0, 0);
            }
        }
        // sigmoid(s-3) and P write: lane holds S^T[k=mt*16+qd*4+rr][q=s2*16+r15]
#pragma unroll
        for (int mt = 0; mt < 4; mt++)
#pragma unroll
            for (int s2 = 0; s2 < 2; s2++) {
                f32x4 sv = accS[mt][s2];
                float p[4];
#pragma unroll
                for (int rr = 0; rr < 4; rr++) {
                    float t = __builtin_fmaf(sv[rr], NLOG2E, BIAS_L2E);
                    float u = __builtin_amdgcn_exp2f(t);
                    p[rr] = __builtin_amdgcn_rcpf(1.0f + u);
                }
                u32 lo = pkbf(p[0], p[1]);
                u32 hi = pkbf(p[2], p[3]);
                u32* dst = (u32*)&Psw[(s2 * 16 + r15) * 72 + mt * 16 + qd * 4];
                dst[0] = lo;
                dst[1] = hi;
            }
        asm volatile("s_waitcnt lgkmcnt(0)" ::: "memory");
        // O += P (32q x 64k) @ V^T (n=d)
#pragma unroll
        for (int ks = 0; ks < 64; ks += 32) {
            int kidx = (ks >> 3) + qd;
            bf16x8 ap0 = *(const bf16x8*)&Psw[(r15)*72 + ks + qd * 8];
            bf16x8 ap1 = *(const bf16x8*)&Psw[(16 + r15) * 72 + ks + qd * 8];
#pragma unroll
            for (int jt = 0; jt < 4; jt++) {
                bf16x8 bv = frag64(Vs, jt * 16 + r15, kidx);
                accO[0][jt] = __builtin_amdgcn_mfma_f32_16x16x32_bf16(ap0, bv, accO[0][jt], 0, 0, 0);
                accO[1][jt] = __builtin_amdgcn_mfma_f32_16x16x32_bf16(ap1, bv, accO[1][jt], 0, 0, 0);
            }
        }
    }

#pragma unroll
    for (int ms = 0; ms < 2; ms++)
#pragma unroll
        for (int rr = 0; rr < 4; rr++) {
            size_t row = (size_t)(b * 2048 + q0 + wave * 32 + ms * 16 + qd * 4 + rr);
#pragma unroll
            for (int jt = 0; jt < 4; jt++)
                ctx[row * 1024 + h * 64 + jt * 16 + r15] = f2bf(accO[ms][jt][rr]);
        }
}

// ---------------------------------------------------------------------------
// V transpose: vb[4096,1024] -> vt[(b*16+h)*64+d][2048] (per-batch k index)
// ---------------------------------------------------------------------------
__global__ __launch_bounds__(256) void transpose_v(const u16* __restrict__ vb, u16* __restrict__ vt) {
    __shared__ u16 T[64 * 72];
    const int kt = blockIdx.x;  // 0..31
    const int bh = blockIdx.y;  // 0..31
    const int b = bh >> 4, h = bh & 15;
    const int tid = threadIdx.x;
    const int sr = tid >> 2, sc = (tid & 3) * 16;
    const u16* src = vb + (size_t)(b * 2048 + kt * 64 + sr) * 1024 + h * 64 + sc;
    *(u16x8*)&T[sr * 72 + sc] = *(const u16x8*)src;
    *(u16x8*)&T[sr * 72 + sc + 8] = *(const u16x8*)(src + 8);
    __syncthreads();
    u16x8 o0, o1;
#pragma unroll
    for (int i = 0; i < 8; i++) o0[i] = T[(sc + i) * 72 + sr];
#pragma unroll
    for (int i = 0; i < 8; i++) o1[i] = T[(sc + 8 + i) * 72 + sr];
    u16* dst = vt + (size_t)(bh * 64 + sr) * 2048 + kt * 64 + sc;
    *(u16x8*)dst = o0;
    *(u16x8*)(dst + 8) = o1;
}

// ---------------------------------------------------------------------------
// Row LayerNorm over D=1024 (fp32 in -> bf16 out)
// ---------------------------------------------------------------------------
__global__ __launch_bounds__(256) void ln_rows_bf16(const float* __restrict__ x,
                                                    const float* __restrict__ sc,
                                                    const float* __restrict__ bs,
                                                    u16* __restrict__ y) {
    __shared__ float s1buf[4], s2buf[4];
    const int row = blockIdx.x;
    const int tid = threadIdx.x;
    const size_t base = (size_t)row * 1024 + tid * 4;
    const float4 xv = *(const float4*)(x + base);
    float s1 = xv.x + xv.y + xv.z + xv.w;
    float s2 = xv.x * xv.x + xv.y * xv.y + xv.z * xv.z + xv.w * xv.w;
    int lane = tid & 63, wave = tid >> 6;
#pragma unroll
    for (int off = 32; off > 0; off >>= 1) {
        s1 += __shfl_down(s1, off, 64);
        s2 += __shfl_down(s2, off, 64);
    }
    if (lane == 0) { s1buf[wave] = s1; s2buf[wave] = s2; }
    __syncthreads();
    s1 = s1buf[0] + s1buf[1] + s1buf[2] + s1buf[3];
    s2 = s2buf[0] + s2buf[1] + s2buf[2] + s2buf[3];
    float mu = s1 * (1.0f / 1024.0f);
    float var = s2 * (1.0f / 1024.0f) - mu * mu;
    float rs = rsqrtf(var + LN_EPS);
    const float4 scv = *(const float4*)(sc + tid * 4);
    const float4 bsv = *(const float4*)(bs + tid * 4);
    u16x4 o;
    o[0] = f2bf((xv.x - mu) * rs * scv.x + bsv.x);
    o[1] = f2bf((xv.y - mu) * rs * scv.y + bsv.y);
    o[2] = f2bf((xv.z - mu) * rs * scv.z + bsv.z);
    o[3] = f2bf((xv.w - mu) * rs * scv.w + bsv.w);
    *(u16x4*)(y + base) = o;
}

// ---------------------------------------------------------------------------
// Per-head LN (bf16 in -> bf16 out, SIG_SCALE folded). grid (16384, 2).
// ---------------------------------------------------------------------------
__global__ __launch_bounds__(256) void head_ln2(const u16* __restrict__ qpre, const u16* __restrict__ kpre,
                                                const float* __restrict__ qs, const float* __restrict__ qb,
                                                const float* __restrict__ ksc, const float* __restrict__ kb,
                                                u16* __restrict__ qln, u16* __restrict__ kln) {
    const int sel = blockIdx.y;
    const u16* x = sel == 0 ? qpre : kpre;
    const float* sc = sel == 0 ? qs : ksc;
    const float* bs = sel == 0 ? qb : kb;
    u16* y = sel == 0 ? qln : kln;
    const int tid = threadIdx.x;
    const int lane = tid & 63;
    const int gw = blockIdx.x * 4 + (tid >> 6);  // row*16 + h
    const size_t idx = (size_t)gw * 64 + lane;
    float v = bf2f(x[idx]);
    float s1 = v, s2 = v * v;
#pragma unroll
    for (int off = 32; off > 0; off >>= 1) {
        s1 += __shfl_xor(s1, off, 64);
        s2 += __shfl_xor(s2, off, 64);
    }
    float mu = s1 * (1.0f / 64.0f);
    float var = s2 * (1.0f / 64.0f) - mu * mu;
    float rs = rsqrtf(var + LN_EPS);
    float o = ((v - mu) * rs * sc[lane] + bs[lane]) * SIG_SCALE_F;
    y[idx] = f2bf(o);
}

// ---------------------------------------------------------------------------
// Final: out = LN(resid + gamma*op) (fp32)
// ---------------------------------------------------------------------------
__global__ __launch_bounds__(256) void final_ln(const float* __restrict__ resid,
                                                const float* __restrict__ op,
                                                const float* __restrict__ gamma,
                                                const float* __restrict__ sc,
                                                const float* __restrict__ bs,
                                                float* __restrict__ out) {
    __shared__ float s1buf[4], s2buf[4];
    const int row = blockIdx.x;
    const int tid = threadIdx.x;
    const size_t base = (size_t)row * 1024 + tid * 4;
    float4 rv = *(const float4*)(resid + base);
    float4 ov = *(const float4*)(op + base);
    float4 gv = *(const float4*)(gamma + tid * 4);
    float4 xv;
    xv.x = rv.x + gv.x * ov.x;
    xv.y = rv.y + gv.y * ov.y;
    xv.z = rv.z + gv.z * ov.z;
    xv.w = rv.w + gv.w * ov.w;
    float s1 = xv.x + xv.y + xv.z + xv.w;
    float s2 = xv.x * xv.x + xv.y * xv.y + xv.z * xv.z + xv.w * xv.w;
    int lane = tid & 63, wave = tid >> 6;
#pragma unroll
    for (int off = 32; off > 0; off >>= 1) {
        s1 += __shfl_down(s1, off, 64);
        s2 += __shfl_down(s2, off, 64);
    }
    if (lane == 0) { s1buf[wave] = s1; s2buf[wave] = s2; }
    __syncthreads();
    s1 = s1buf[0] + s1buf[1] + s1buf[2] + s1buf[3];
    s2 = s2buf[0] + s2buf[1] + s2buf[2] + s2buf[3];
    float mu = s1 * (1.0f / 1024.0f);
    float var = s2 * (1.0f / 1024.0f) - mu * mu;
    float rs = rsqrtf(var + LN_EPS);
    const float4 scv = *(const float4*)(sc + tid * 4);
    const float4 bsv = *(const float4*)(bs + tid * 4);
    float4 o;
    o.x = (xv.x - mu) * rs * scv.x + bsv.x;
    o.y = (xv.y - mu) * rs * scv.y + bsv.y;
    o.z = (xv.z - mu) * rs * scv.z + bsv.z;
    o.w = (xv.w - mu) * rs * scv.w + bsv.w;
    *(float4*)(out + base) = o;
}

// fp32 -> bf16 converts
__global__ __launch_bounds__(256) void conv_bf16(const float* __restrict__ x,
                                                 u16* __restrict__ y, int n4) {
    int i = blockIdx.x * 256 + threadIdx.x;
    if (i < n4) {
        float4 xv = *(const float4*)(x + (size_t)i * 4);
        u16x4 o;
        o[0] = f2bf(xv.x);
        o[1] = f2bf(xv.y);
        o[2] = f2bf(xv.z);
        o[3] = f2bf(xv.w);
        *(u16x4*)(y + (size_t)i * 4) = o;
    }
}

// all four 1024x1024 weights in one launch: grid (1024, 4)
__global__ __launch_bounds__(256) void conv_w4(const float* __restrict__ w0, const float* __restrict__ w1,
                                               const float* __restrict__ w2, const float* __restrict__ w3,
                                               u16* __restrict__ dst) {
    const int y = blockIdx.y;
    const float* src = (y == 0) ? w0 : ((y == 1) ? w1 : ((y == 2) ? w2 : w3));
    u16* d = dst + (size_t)y * 1048576;
    int i = blockIdx.x * 256 + threadIdx.x;  // < 262144
    float4 xv = *(const float4*)(src + (size_t)i * 4);
    u16x4 o;
    o[0] = f2bf(xv.x);
    o[1] = f2bf(xv.y);
    o[2] = f2bf(xv.z);
    o[3] = f2bf(xv.w);
    *(u16x4*)(d + (size_t)i * 4) = o;
}

extern "C" void kernel_launch(void* const* d_in, const int* in_sizes, int n_in,
                              void* d_out, int out_size, void* d_ws, size_t ws_size,
                              hipStream_t stream) {
    const float* qf    = (const float*)d_in[0];
    const float* kf    = (const float*)d_in[1];
    const float* Wq    = (const float*)d_in[2];
    const float* Wk    = (const float*)d_in[3];
    const float* Wv    = (const float*)d_in[4];
    const float* Wo    = (const float*)d_in[5];
    const float* qn_s  = (const float*)d_in[6];
    const float* qn_b  = (const float*)d_in[7];
    const float* kn_s  = (const float*)d_in[8];
    const float* kn_b  = (const float*)d_in[9];
    const float* lnq_s = (const float*)d_in[10];
    const float* lnq_b = (const float*)d_in[11];
    const float* lno_s = (const float*)d_in[12];
    const float* lno_b = (const float*)d_in[13];
    const float* gamma = (const float*)d_in[14];
    float* out = (float*)d_out;

    char* ws = (char*)d_ws;
    const size_t MB = 1024 * 1024;
    // lifetimes: xq/keyb dead after gemm_qkv; qpre/kpre dead after head_ln2;
    // vb dead after transpose_v; qln/kln/vt dead after attn; ctx dead after gemm_o
    u16* Wqb   = (u16*)(ws + 0 * MB);   // ..8MB: 4 weights
    u16* Wkb   = (u16*)(ws + 2 * MB);
    u16* Wvb   = (u16*)(ws + 4 * MB);
    u16* Wob   = (u16*)(ws + 6 * MB);
    u16* xq    = (u16*)(ws + 8 * MB);
    u16* qln   = (u16*)(ws + 8 * MB);   // reuse xq
    u16* keyb  = (u16*)(ws + 16 * MB);
    u16* kln   = (u16*)(ws + 16 * MB);  // reuse keyb
    u16* qpre  = (u16*)(ws + 24 * MB);
    u16* vt    = (u16*)(ws + 24 * MB);  // reuse qpre
    u16* kpre  = (u16*)(ws + 32 * MB);
    u16* ctx   = (u16*)(ws + 32 * MB);  // reuse kpre
    u16* vb    = (u16*)(ws + 40 * MB);
    float* opre = (float*)(ws + 40 * MB); // reuse vb (16MB, ends at 56MB)

    conv_w4<<<dim3(1024, 4), 256, 0, stream>>>(Wq, Wk, Wv, Wo, Wqb);
    conv_bf16<<<dim3(4096), 256, 0, stream>>>(kf, keyb, 1048576);
    ln_rows_bf16<<<dim3(4096), 256, 0, stream>>>(qf, lnq_s, lnq_b, xq);

    gemm_qkv<<<dim3(32, 8, 3), 256, 0, stream>>>(xq, keyb, Wqb, Wkb, Wvb, qpre, kpre, vb);

    head_ln2<<<dim3(16384, 2), 256, 0, stream>>>(qpre, kpre, qn_s, qn_b, kn_s, kn_b, qln, kln);
    transpose_v<<<dim3(32, 32), 256, 0, stream>>>(vb, vt);

    attn_sigmoid_v2<<<dim3(16, 16, 2), 256, 0, stream>>>(qln, kln, vt, ctx);

    gemm_o<<<dim3(32, 8), 256, 0, stream>>>(ctx, Wob, opre);
    final_ln<<<dim3(4096), 256, 0, stream>>>(qf, opre, gamma, lno_s, lno_b, out);
}

// Round 4
// 250.238 us; speedup vs baseline: 1.5465x; 1.1267x over previous
//
#include <hip/hip_runtime.h>

typedef unsigned short u16;
typedef unsigned int u32;
typedef __bf16 bf16x8 __attribute__((ext_vector_type(8)));
typedef float f32x4 __attribute__((ext_vector_type(4)));
typedef u16 u16x8 __attribute__((ext_vector_type(8)));
typedef u16 u16x4 __attribute__((ext_vector_type(4)));

#define LN_EPS 1e-5f
#define SIG_SCALE_F 0.35355339059327379f /* 64^-0.25 */
#define NLOG2E -1.4426950408889634f
#define BIAS_L2E 4.328085122666891f /* 3*log2(e) */

__device__ __forceinline__ u16 f2bf(float f) {
    u32 u = __builtin_bit_cast(u32, f);
    u32 r = u + 0x7fffu + ((u >> 16) & 1u);
    return (u16)(r >> 16);
}
__device__ __forceinline__ float bf2f(u16 v) {
    return __builtin_bit_cast(float, (u32)v << 16);
}
// pack high-16s of two f32 (truncating bf16 cvt, 1 instr): low16=a, high16=b
__device__ __forceinline__ u32 pk_hi(float a, float b) {
    return __builtin_amdgcn_perm(__builtin_bit_cast(u32, a), __builtin_bit_cast(u32, b),
                                 0x03020706u);
}

// async global->LDS, 16B per lane; lds base wave-uniform (HW adds lane*16)
__device__ __forceinline__ void gload16(const u16* g, u16* lds) {
    __builtin_amdgcn_global_load_lds(
        (const __attribute__((address_space(1))) u32*)g,
        (__attribute__((address_space(3))) u32*)lds, 16, 0, 0);
}

// ---------------------------------------------------------------------------
// GEMM core: acc[4][4] += A[M,K] @ B[N,K]^T 128x128 tile, BK=32,
// global_load_lds staging, XOR-swizzled LDS (64B rows, chunk c^=row&3).
// ---------------------------------------------------------------------------
__device__ __forceinline__ void gemm_core(f32x4 acc[4][4],
                                          const u16* __restrict__ A, const u16* __restrict__ B,
                                          int Kiter, int lda, int ldb,
                                          long m0, long n0, u16* As, u16* Bs) {
    const int tid = threadIdx.x;
    const int lane = tid & 63;
    const int wave = tid >> 6;
    const int r15 = lane & 15;
    const int qd = lane >> 4;
    const int wm = (wave >> 1) * 64;
    const int wn = (wave & 1) * 64;

    const int srow = wave * 16 + (lane >> 2);
    const int c0 = (lane & 3) ^ (srow & 3);
    const u16* Ap0 = A + (m0 + srow) * lda + c0 * 8;
    const u16* Ap1 = A + (m0 + srow + 64) * lda + c0 * 8;
    const u16* Bp0 = B + (n0 + srow) * ldb + c0 * 8;
    const u16* Bp1 = B + (n0 + srow + 64) * ldb + c0 * 8;
    u16* As0 = As + wave * 512;
    u16* As1 = As + (wave + 4) * 512;
    u16* Bs0 = Bs + wave * 512;
    u16* Bs1 = Bs + (wave + 4) * 512;

    for (int kt = 0; kt < Kiter; kt += 32) {
        __syncthreads();
        gload16(Ap0 + kt, As0);
        gload16(Ap1 + kt, As1);
        gload16(Bp0 + kt, Bs0);
        gload16(Bp1 + kt, Bs1);
        __syncthreads();
        bf16x8 af[4], bfr[4];
#pragma unroll
        for (int i = 0; i < 4; i++) {
            int row = wm + i * 16 + r15;
            af[i] = *(const bf16x8*)(As + row * 32 + ((qd ^ (row & 3)) * 8));
        }
#pragma unroll
        for (int j = 0; j < 4; j++) {
            int row = wn + j * 16 + r15;
            bfr[j] = *(const bf16x8*)(Bs + row * 32 + ((qd ^ (row & 3)) * 8));
        }
#pragma unroll
        for (int i = 0; i < 4; i++)
#pragma unroll
            for (int j = 0; j < 4; j++)
                acc[i][j] = __builtin_amdgcn_mfma_f32_16x16x32_bf16(af[i], bfr[j], acc[i][j], 0, 0, 0);
    }
}

// ---------------------------------------------------------------------------
// Fused q/k/v projections with per-head LayerNorm epilogue for q,k.
// grid (32, 8, 3). Each wave's 64-col span == exactly one head, so head-LN
// stats reduce over 4 regs + shfl_xor(1,2,4,8) (r15 bits) within the wave.
// ---------------------------------------------------------------------------
__global__ __launch_bounds__(256) void gemm_qkv(const u16* __restrict__ xq, const u16* __restrict__ keyb,
                                                const u16* __restrict__ Wqb, const u16* __restrict__ Wkb,
                                                const u16* __restrict__ Wvb,
                                                const float* __restrict__ qns, const float* __restrict__ qnb,
                                                const float* __restrict__ kns, const float* __restrict__ knb,
                                                u16* __restrict__ qln, u16* __restrict__ kln,
                                                u16* __restrict__ vb) {
    __shared__ __attribute__((aligned(16))) u16 As[128 * 32];
    __shared__ __attribute__((aligned(16))) u16 Bs[128 * 32];
    const int z = blockIdx.z;
    const u16* A = (z == 0) ? xq : keyb;
    const u16* B = (z == 0) ? Wqb : ((z == 1) ? Wkb : Wvb);
    u16* C = (z == 0) ? qln : ((z == 1) ? kln : vb);
    const long m0 = (long)blockIdx.x * 128;
    const long n0 = (long)blockIdx.y * 128;

    f32x4 acc[4][4];
#pragma unroll
    for (int i = 0; i < 4; i++)
#pragma unroll
        for (int j = 0; j < 4; j++) acc[i][j] = (f32x4){0.f, 0.f, 0.f, 0.f};

    gemm_core(acc, A, B, 1024, 1024, 1024, m0, n0, As, Bs);

    const int lane = threadIdx.x & 63;
    const int wave = threadIdx.x >> 6;
    const int r15 = lane & 15;
    const int qd = lane >> 4;
    const int wm = (wave >> 1) * 64;
    const int wn = (wave & 1) * 64;

    if (z <= 1) {
        const float* sc_ = (z == 0) ? qns : kns;
        const float* bs_ = (z == 0) ? qnb : knb;
        float scl[4], bia[4];
#pragma unroll
        for (int j = 0; j < 4; j++) {
            scl[j] = sc_[j * 16 + r15] * SIG_SCALE_F;
            bia[j] = bs_[j * 16 + r15] * SIG_SCALE_F;
        }
#pragma unroll
        for (int i = 0; i < 4; i++) {
#pragma unroll
            for (int rr = 0; rr < 4; rr++) {
                float a0 = acc[i][0][rr], a1 = acc[i][1][rr], a2 = acc[i][2][rr], a3 = acc[i][3][rr];
                float s1 = (a0 + a1) + (a2 + a3);
                float s2 = __builtin_fmaf(a3, a3,
                           __builtin_fmaf(a2, a2, __builtin_fmaf(a1, a1, a0 * a0)));
#pragma unroll
                for (int off = 1; off <= 8; off <<= 1) {
                    s1 += __shfl_xor(s1, off, 64);
                    s2 += __shfl_xor(s2, off, 64);
                }
                float mu = s1 * (1.0f / 64.0f);
                float var = __builtin_fmaf(-mu, mu, s2 * (1.0f / 64.0f));
                float rs = rsqrtf(var + LN_EPS);
                long row = m0 + wm + i * 16 + qd * 4 + rr;
#pragma unroll
                for (int j = 0; j < 4; j++) {
                    long col = n0 + wn + j * 16 + r15;
                    float o = __builtin_fmaf((acc[i][j][rr] - mu) * rs, scl[j], bia[j]);
                    C[row * 1024 + col] = f2bf(o);
                }
            }
        }
    } else {
#pragma unroll
        for (int i = 0; i < 4; i++)
#pragma unroll
            for (int rr = 0; rr < 4; rr++) {
                long row = m0 + wm + i * 16 + qd * 4 + rr;
#pragma unroll
                for (int j = 0; j < 4; j++)
                    C[row * 1024 + n0 + wn + j * 16 + r15] = f2bf(acc[i][j][rr]);
            }
    }
}

// output projection, split-K=2: grid (32, 8, 2), bf16 partials
__global__ __launch_bounds__(256) void gemm_o(const u16* __restrict__ ctx, const u16* __restrict__ Wob,
                                              u16* __restrict__ opre0, u16* __restrict__ opre1) {
    __shared__ __attribute__((aligned(16))) u16 As[128 * 32];
    __shared__ __attribute__((aligned(16))) u16 Bs[128 * 32];
    const int z = blockIdx.z;
    const int koff = z * 512;
    u16* C = z ? opre1 : opre0;
    const long m0 = (long)blockIdx.x * 128;
    const long n0 = (long)blockIdx.y * 128;
    f32x4 acc[4][4];
#pragma unroll
    for (int i = 0; i < 4; i++)
#pragma unroll
        for (int j = 0; j < 4; j++) acc[i][j] = (f32x4){0.f, 0.f, 0.f, 0.f};
    gemm_core(acc, ctx + koff, Wob + koff, 512, 1024, 1024, m0, n0, As, Bs);

    const int lane = threadIdx.x & 63;
    const int wave = threadIdx.x >> 6;
    const int r15 = lane & 15;
    const int qd = lane >> 4;
    const int wm = (wave >> 1) * 64;
    const int wn = (wave & 1) * 64;
#pragma unroll
    for (int i = 0; i < 4; i++)
#pragma unroll
        for (int rr = 0; rr < 4; rr++) {
            long row = m0 + wm + i * 16 + qd * 4 + rr;
#pragma unroll
            for (int j = 0; j < 4; j++)
                C[row * 1024 + n0 + wn + j * 16 + r15] = f2bf(acc[i][j][rr]);
        }
}

// ---------------------------------------------------------------------------
// Fused sigmoid attention v3. Grid (32, 16, 2): x = qtile(0..15) | kh<<4.
// 4 waves x 32 q-rows, K-chunks of 64, PV in two 32-k subchunks (halves Ps).
// LDS = 16K(Q) + 8K(K) + 8K(V) + 8K(P) = 40KB -> 4 blocks/CU.
// ---------------------------------------------------------------------------
__device__ __forceinline__ bf16x8 frag64(const u16* base, int row, int kidx) {
    return *(const bf16x8*)(base + row * 64 + ((kidx ^ (row & 7)) * 8));
}

__global__ __launch_bounds__(256, 4) void attn_sigmoid_v3(const u16* __restrict__ q,
                                                          const u16* __restrict__ k,
                                                          const u16* __restrict__ vt,
                                                          u16* __restrict__ ctx0,
                                                          u16* __restrict__ ctx1) {
    __shared__ __attribute__((aligned(16))) u16 Qs[128 * 64];
    __shared__ __attribute__((aligned(16))) u16 Ks[64 * 64];
    __shared__ __attribute__((aligned(16))) u16 Vs[64 * 64];
    __shared__ __attribute__((aligned(16))) u16 Ps[4 * 32 * 32];
    const int tid = threadIdx.x;
    const int lane = tid & 63;
    const int wave = tid >> 6;
    const int r15 = lane & 15;
    const int qd = lane >> 4;
    const int q0 = (blockIdx.x & 15) * 128;
    const int kh = blockIdx.x >> 4;
    const int h = blockIdx.y;
    const int b = blockIdx.z;
    const int bh = b * 16 + h;
    u16* ctx = kh ? ctx1 : ctx0;
    u16* PsW = Ps + wave * 1024;

    const int lr0 = lane >> 3;
    const int lc0 = lane & 7;
    {   // stage Q tile 128x64 (sync covered by first in-loop barrier)
#pragma unroll
        for (int i = 0; i < 4; i++) {
            int s = wave * 4 + i;
            int row = s * 8 + lr0;
            int c = lc0 ^ (row & 7);
            gload16(q + (size_t)(b * 2048 + q0 + row) * 1024 + h * 64 + c * 8, Qs + s * 512);
        }
    }

    f32x4 accO[2][4];
#pragma unroll
    for (int ms = 0; ms < 2; ms++)
#pragma unroll
        for (int jt = 0; jt < 4; jt++) accO[ms][jt] = (f32x4){0.f, 0.f, 0.f, 0.f};

    const int kbeg = kh * 1024;
    for (int kc = kbeg; kc < kbeg + 1024; kc += 64) {
        __syncthreads();
#pragma unroll
        for (int i = 0; i < 2; i++) {
            int s = wave * 2 + i;
            int row = s * 8 + lr0;
            int c = lc0 ^ (row & 7);
            gload16(k + (size_t)(b * 2048 + kc + row) * 1024 + h * 64 + c * 8, Ks + s * 512);
            gload16(vt + (size_t)(bh * 64 + row) * 2048 + kc + c * 8, Vs + s * 512);
        }
        __syncthreads();

        // preload Q B-frags for both d-halves
        bf16x8 qf[2][2];
#pragma unroll
        for (int ks2 = 0; ks2 < 2; ks2++)
#pragma unroll
            for (int s2 = 0; s2 < 2; s2++)
                qf[ks2][s2] = frag64(Qs, wave * 32 + s2 * 16 + r15, ks2 * 4 + qd);

#pragma unroll
        for (int half = 0; half < 2; half++) {
            // S^T for k-rows [half*32, half*32+32): A=K, B=Q
            f32x4 aS[2][2];
#pragma unroll
            for (int mtl = 0; mtl < 2; mtl++)
#pragma unroll
                for (int s2 = 0; s2 < 2; s2++) aS[mtl][s2] = (f32x4){0.f, 0.f, 0.f, 0.f};
#pragma unroll
            for (int ks2 = 0; ks2 < 2; ks2++) {
#pragma unroll
                for (int mtl = 0; mtl < 2; mtl++) {
                    bf16x8 ak = frag64(Ks, (half * 2 + mtl) * 16 + r15, ks2 * 4 + qd);
                    aS[mtl][0] = __builtin_amdgcn_mfma_f32_16x16x32_bf16(ak, qf[ks2][0], aS[mtl][0], 0, 0, 0);
                    aS[mtl][1] = __builtin_amdgcn_mfma_f32_16x16x32_bf16(ak, qf[ks2][1], aS[mtl][1], 0, 0, 0);
                }
            }
            // sigmoid + P write (swizzled, wave-private)
#pragma unroll
            for (int mtl = 0; mtl < 2; mtl++)
#pragma unroll
                for (int s2 = 0; s2 < 2; s2++) {
                    f32x4 sv = aS[mtl][s2];
                    float p[4];
#pragma unroll
                    for (int rr = 0; rr < 4; rr++) {
                        float t = __builtin_fmaf(sv[rr], NLOG2E, BIAS_L2E);
                        float u = __builtin_amdgcn_exp2f(t);
                        p[rr] = __builtin_amdgcn_rcpf(1.0f + u);
                    }
                    int row = s2 * 16 + r15;
                    int c8 = (mtl * 4 + qd) ^ ((row & 3) << 1);
                    uint2 st;
                    st.x = pk_hi(p[0], p[1]);
                    st.y = pk_hi(p[2], p[3]);
                    *(uint2*)(PsW + row * 32 + c8 * 4) = st;
                }
            asm volatile("s_waitcnt lgkmcnt(0)" ::: "memory");
            // O += P[:, half] @ V[half, :]
            bf16x8 bv[4];
#pragma unroll
            for (int jt = 0; jt < 4; jt++) bv[jt] = frag64(Vs, jt * 16 + r15, half * 4 + qd);
#pragma unroll
            for (int ms = 0; ms < 2; ms++) {
                int prow = ms * 16 + r15;
                int pc16 = qd ^ (prow & 3);
                bf16x8 ap = *(const bf16x8*)(PsW + prow * 32 + pc16 * 8);
#pragma unroll
                for (int jt = 0; jt < 4; jt++)
                    accO[ms][jt] = __builtin_amdgcn_mfma_f32_16x16x32_bf16(ap, bv[jt], accO[ms][jt], 0, 0, 0);
            }
        }
    }

#pragma unroll
    for (int ms = 0; ms < 2; ms++)
#pragma unroll
        for (int rr = 0; rr < 4; rr++) {
            size_t row = (size_t)(b * 2048 + q0 + wave * 32 + ms * 16 + qd * 4 + rr);
#pragma unroll
            for (int jt = 0; jt < 4; jt++)
                ctx[row * 1024 + h * 64 + jt * 16 + r15] = f2bf(accO[ms][jt][rr]);
        }
}

// ctx = ctx0 + ctx1 (bf16), 8 elems/thread
__global__ __launch_bounds__(256) void ctx_merge(const u16* __restrict__ a, const u16* __restrict__ b,
                                                 u16* __restrict__ c) {
    size_t i = ((size_t)blockIdx.x * 256 + threadIdx.x) * 8;
    u16x8 av = *(const u16x8*)(a + i);
    u16x8 bv = *(const u16x8*)(b + i);
    u16x8 o;
#pragma unroll
    for (int e = 0; e < 8; e++) o[e] = f2bf(bf2f(av[e]) + bf2f(bv[e]));
    *(u16x8*)(c + i) = o;
}

// ---------------------------------------------------------------------------
// V transpose: vb[4096,1024] -> vt[(b*16+h)*64+d][2048]
// ---------------------------------------------------------------------------
__global__ __launch_bounds__(256) void transpose_v(const u16* __restrict__ vb, u16* __restrict__ vt) {
    __shared__ u16 T[64 * 72];
    const int kt = blockIdx.x;
    const int bh = blockIdx.y;
    const int b = bh >> 4, h = bh & 15;
    const int tid = threadIdx.x;
    const int sr = tid >> 2, sc = (tid & 3) * 16;
    const u16* src = vb + (size_t)(b * 2048 + kt * 64 + sr) * 1024 + h * 64 + sc;
    *(u16x8*)&T[sr * 72 + sc] = *(const u16x8*)src;
    *(u16x8*)&T[sr * 72 + sc + 8] = *(const u16x8*)(src + 8);
    __syncthreads();
    u16x8 o0, o1;
#pragma unroll
    for (int i = 0; i < 8; i++) o0[i] = T[(sc + i) * 72 + sr];
#pragma unroll
    for (int i = 0; i < 8; i++) o1[i] = T[(sc + 8 + i) * 72 + sr];
    u16* dst = vt + (size_t)(bh * 64 + sr) * 2048 + kt * 64 + sc;
    *(u16x8*)dst = o0;
    *(u16x8*)(dst + 8) = o1;
}

// ---------------------------------------------------------------------------
// Row LayerNorm over D=1024 (fp32 in -> bf16 out)
// ---------------------------------------------------------------------------
__global__ __launch_bounds__(256) void ln_rows_bf16(const float* __restrict__ x,
                                                    const float* __restrict__ sc,
                                                    const float* __restrict__ bs,
                                                    u16* __restrict__ y) {
    __shared__ float s1buf[4], s2buf[4];
    const int row = blockIdx.x;
    const int tid = threadIdx.x;
    const size_t base = (size_t)row * 1024 + tid * 4;
    const float4 xv = *(const float4*)(x + base);
    float s1 = xv.x + xv.y + xv.z + xv.w;
    float s2 = xv.x * xv.x + xv.y * xv.y + xv.z * xv.z + xv.w * xv.w;
    int lane = tid & 63, wave = tid >> 6;
#pragma unroll
    for (int off = 32; off > 0; off >>= 1) {
        s1 += __shfl_down(s1, off, 64);
        s2 += __shfl_down(s2, off, 64);
    }
    if (lane == 0) { s1buf[wave] = s1; s2buf[wave] = s2; }
    __syncthreads();
    s1 = s1buf[0] + s1buf[1] + s1buf[2] + s1buf[3];
    s2 = s2buf[0] + s2buf[1] + s2buf[2] + s2buf[3];
    float mu = s1 * (1.0f / 1024.0f);
    float var = s2 * (1.0f / 1024.0f) - mu * mu;
    float rs = rsqrtf(var + LN_EPS);
    const float4 scv = *(const float4*)(sc + tid * 4);
    const float4 bsv = *(const float4*)(bs + tid * 4);
    u16x4 o;
    o[0] = f2bf((xv.x - mu) * rs * scv.x + bsv.x);
    o[1] = f2bf((xv.y - mu) * rs * scv.y + bsv.y);
    o[2] = f2bf((xv.z - mu) * rs * scv.z + bsv.z);
    o[3] = f2bf((xv.w - mu) * rs * scv.w + bsv.w);
    *(u16x4*)(y + base) = o;
}

// ---------------------------------------------------------------------------
// Final: out = LN(resid + gamma*(o0+o1)) (fp32, bf16 partials)
// ---------------------------------------------------------------------------
__global__ __launch_bounds__(256) void final_ln(const float* __restrict__ resid,
                                                const u16* __restrict__ o0,
                                                const u16* __restrict__ o1,
                                                const float* __restrict__ gamma,
                                                const float* __restrict__ sc,
                                                const float* __restrict__ bs,
                                                float* __restrict__ out) {
    __shared__ float s1buf[4], s2buf[4];
    const int row = blockIdx.x;
    const int tid = threadIdx.x;
    const size_t base = (size_t)row * 1024 + tid * 4;
    float4 rv = *(const float4*)(resid + base);
    u16x4 p0 = *(const u16x4*)(o0 + base);
    u16x4 p1 = *(const u16x4*)(o1 + base);
    float4 gv = *(const float4*)(gamma + tid * 4);
    float4 xv;
    xv.x = rv.x + gv.x * (bf2f(p0[0]) + bf2f(p1[0]));
    xv.y = rv.y + gv.y * (bf2f(p0[1]) + bf2f(p1[1]));
    xv.z = rv.z + gv.z * (bf2f(p0[2]) + bf2f(p1[2]));
    xv.w = rv.w + gv.w * (bf2f(p0[3]) + bf2f(p1[3]));
    float s1 = xv.x + xv.y + xv.z + xv.w;
    float s2 = xv.x * xv.x + xv.y * xv.y + xv.z * xv.z + xv.w * xv.w;
    int lane = tid & 63, wave = tid >> 6;
#pragma unroll
    for (int off = 32; off > 0; off >>= 1) {
        s1 += __shfl_down(s1, off, 64);
        s2 += __shfl_down(s2, off, 64);
    }
    if (lane == 0) { s1buf[wave] = s1; s2buf[wave] = s2; }
    __syncthreads();
    s1 = s1buf[0] + s1buf[1] + s1buf[2] + s1buf[3];
    s2 = s2buf[0] + s2buf[1] + s2buf[2] + s2buf[3];
    float mu = s1 * (1.0f / 1024.0f);
    float var = s2 * (1.0f / 1024.0f) - mu * mu;
    float rs = rsqrtf(var + LN_EPS);
    const float4 scv = *(const float4*)(sc + tid * 4);
    const float4 bsv = *(const float4*)(bs + tid * 4);
    float4 o;
    o.x = (xv.x - mu) * rs * scv.x + bsv.x;
    o.y = (xv.y - mu) * rs * scv.y + bsv.y;
    o.z = (xv.z - mu) * rs * scv.z + bsv.z;
    o.w = (xv.w - mu) * rs * scv.w + bsv.w;
    *(float4*)(out + base) = o;
}

// fp32 -> bf16 converts
__global__ __launch_bounds__(256) void conv_bf16(const float* __restrict__ x,
                                                 u16* __restrict__ y, int n4) {
    int i = blockIdx.x * 256 + threadIdx.x;
    if (i < n4) {
        float4 xv = *(const float4*)(x + (size_t)i * 4);
        u16x4 o;
        o[0] = f2bf(xv.x);
        o[1] = f2bf(xv.y);
        o[2] = f2bf(xv.z);
        o[3] = f2bf(xv.w);
        *(u16x4*)(y + (size_t)i * 4) = o;
    }
}

// all four 1024x1024 weights in one launch: grid (1024, 4)
__global__ __launch_bounds__(256) void conv_w4(const float* __restrict__ w0, const float* __restrict__ w1,
                                               const float* __restrict__ w2, const float* __restrict__ w3,
                                               u16* __restrict__ dst) {
    const int y = blockIdx.y;
    const float* src = (y == 0) ? w0 : ((y == 1) ? w1 : ((y == 2) ? w2 : w3));
    u16* d = dst + (size_t)y * 1048576;
    int i = blockIdx.x * 256 + threadIdx.x;
    float4 xv = *(const float4*)(src + (size_t)i * 4);
    u16x4 o;
    o[0] = f2bf(xv.x);
    o[1] = f2bf(xv.y);
    o[2] = f2bf(xv.z);
    o[3] = f2bf(xv.w);
    *(u16x4*)(d + (size_t)i * 4) = o;
}

extern "C" void kernel_launch(void* const* d_in, const int* in_sizes, int n_in,
                              void* d_out, int out_size, void* d_ws, size_t ws_size,
                              hipStream_t stream) {
    const float* qf    = (const float*)d_in[0];
    const float* kf    = (const float*)d_in[1];
    const float* Wq    = (const float*)d_in[2];
    const float* Wk    = (const float*)d_in[3];
    const float* Wv    = (const float*)d_in[4];
    const float* Wo    = (const float*)d_in[5];
    const float* qn_s  = (const float*)d_in[6];
    const float* qn_b  = (const float*)d_in[7];
    const float* kn_s  = (const float*)d_in[8];
    const float* kn_b  = (const float*)d_in[9];
    const float* lnq_s = (const float*)d_in[10];
    const float* lnq_b = (const float*)d_in[11];
    const float* lno_s = (const float*)d_in[12];
    const float* lno_b = (const float*)d_in[13];
    const float* gamma = (const float*)d_in[14];
    float* out = (float*)d_out;

    char* ws = (char*)d_ws;
    const size_t MB = 1024 * 1024;
    // 64 MiB layout with lifetime reuse:
    u16* Wqb   = (u16*)(ws + 0 * MB);
    u16* Wkb   = (u16*)(ws + 2 * MB);
    u16* Wvb   = (u16*)(ws + 4 * MB);
    u16* Wob   = (u16*)(ws + 6 * MB);
    u16* xq    = (u16*)(ws + 8 * MB);    // dead after gemm_qkv
    u16* ctx   = (u16*)(ws + 8 * MB);    // reuse xq (written by ctx_merge)
    u16* keyb  = (u16*)(ws + 16 * MB);   // dead after gemm_qkv
    u16* opre0 = (u16*)(ws + 16 * MB);   // reuse keyb (written by gemm_o)
    u16* qln   = (u16*)(ws + 24 * MB);   // dead after attn
    u16* opre1 = (u16*)(ws + 24 * MB);   // reuse qln (written by gemm_o)
    u16* kln   = (u16*)(ws + 32 * MB);   // dead after attn
    u16* vb    = (u16*)(ws + 40 * MB);   // dead after transpose_v
    u16* ctx1  = (u16*)(ws + 40 * MB);   // reuse vb (written by attn)
    u16* vt    = (u16*)(ws + 48 * MB);   // dead after attn
    u16* ctx0  = (u16*)(ws + 56 * MB);

    conv_w4<<<dim3(1024, 4), 256, 0, stream>>>(Wq, Wk, Wv, Wo, Wqb);
    conv_bf16<<<dim3(4096), 256, 0, stream>>>(kf, keyb, 1048576);
    ln_rows_bf16<<<dim3(4096), 256, 0, stream>>>(qf, lnq_s, lnq_b, xq);

    gemm_qkv<<<dim3(32, 8, 3), 256, 0, stream>>>(xq, keyb, Wqb, Wkb, Wvb,
                                                 qn_s, qn_b, kn_s, kn_b, qln, kln, vb);

    transpose_v<<<dim3(32, 32), 256, 0, stream>>>(vb, vt);

    attn_sigmoid_v3<<<dim3(32, 16, 2), 256, 0, stream>>>(qln, kln, vt, ctx0, ctx1);
    ctx_merge<<<dim3(2048), 256, 0, stream>>>(ctx0, ctx1, ctx);

    gemm_o<<<dim3(32, 8, 2), 256, 0, stream>>>(ctx, Wob, opre0, opre1);
    final_ln<<<dim3(4096), 256, 0, stream>>>(qf, opre0, opre1, gamma, lno_s, lno_b, out);
}